// Round 3
// baseline (916.487 us; speedup 1.0000x reference)
//
#include <hip/hip_runtime.h>
#include <math.h>

// Problem constants
constexpr int BATCH = 2;
constexpr int SEQ   = 2048;
constexpr int HID   = 1024;
constexpr int NHEAD = 16;
constexpr int HDIM  = 64;
constexpr int MTOT  = BATCH * SEQ;        // 4096
constexpr int BH    = BATCH * NHEAD;      // 32

// ---------------------------------------------------------------------------
// GEMM: C = A[M,1024] @ W[1024,1024] + bias   (fp32, 64x64 tile, 256 thr, 4x4)
// MODE 0: plain row-major output [M,1024]
// MODE 1: head-split output  [B, nh, S, hd]
// MODE 2: like 1, but W := W - W2, bias := bias - bias2 (fused dif = q - k)
// ---------------------------------------------------------------------------
template<int MODE>
__global__ __launch_bounds__(256) void gemm_k(const float* __restrict__ A,
                                              const float* __restrict__ W,
                                              const float* __restrict__ W2,
                                              const float* __restrict__ bias,
                                              const float* __restrict__ bias2,
                                              float* __restrict__ C) {
    __shared__ float As[16][68];   // [k][m] transposed, padded pitch 68
    __shared__ float Bs[16][68];   // [k][n], padded pitch 68

    const int t  = threadIdx.x;
    const int m0 = blockIdx.x * 64;
    const int n0 = blockIdx.y * 64;
    const int tx = t & 15;         // col group (4 cols)
    const int ty = t >> 4;         // row group (4 rows)

    // staging indices
    const int arow = t >> 2;       // 0..63  (A tile row)
    const int akq  = t & 3;        // 0..3   (k float4 within 16)
    const int bkr  = t >> 4;       // 0..15  (W tile k-row)
    const int bnq  = t & 15;       // 0..15  (n float4 within 64)

    float acc[4][4] = {};

    for (int k0 = 0; k0 < HID; k0 += 16) {
        float4 a4 = *(const float4*)(A + (m0 + arow) * HID + k0 + akq * 4);
        float4 b4 = *(const float4*)(W + (k0 + bkr) * HID + n0 + bnq * 4);
        if (MODE == 2) {
            float4 c4 = *(const float4*)(W2 + (k0 + bkr) * HID + n0 + bnq * 4);
            b4.x -= c4.x; b4.y -= c4.y; b4.z -= c4.z; b4.w -= c4.w;
        }
        __syncthreads();   // previous iteration's reads complete
        As[akq * 4 + 0][arow] = a4.x;
        As[akq * 4 + 1][arow] = a4.y;
        As[akq * 4 + 2][arow] = a4.z;
        As[akq * 4 + 3][arow] = a4.w;
        *(float4*)(&Bs[bkr][bnq * 4]) = b4;
        __syncthreads();

#pragma unroll
        for (int kk = 0; kk < 16; kk++) {
            float4 av = *(const float4*)(&As[kk][ty * 4]);
            float4 bv = *(const float4*)(&Bs[kk][tx * 4]);
            float ar[4] = {av.x, av.y, av.z, av.w};
            float br[4] = {bv.x, bv.y, bv.z, bv.w};
#pragma unroll
            for (int i = 0; i < 4; i++)
#pragma unroll
                for (int j = 0; j < 4; j++)
                    acc[i][j] += ar[i] * br[j];
        }
    }

    // bias
    float4 bv = *(const float4*)(bias + n0 + tx * 4);
    if (MODE == 2) {
        float4 b2 = *(const float4*)(bias2 + n0 + tx * 4);
        bv.x -= b2.x; bv.y -= b2.y; bv.z -= b2.z; bv.w -= b2.w;
    }

#pragma unroll
    for (int i = 0; i < 4; i++) {
        const int m = m0 + ty * 4 + i;
        float4 out;
        out.x = acc[i][0] + bv.x;
        out.y = acc[i][1] + bv.y;
        out.z = acc[i][2] + bv.z;
        out.w = acc[i][3] + bv.w;
        if (MODE == 0) {
            *(float4*)(C + m * HID + n0 + tx * 4) = out;
        } else {
            const int b_idx = m >> 11;         // m / 2048
            const int s_idx = m & 2047;
            const int h     = n0 >> 6;         // head (tile width == hd)
            *(float4*)(C + b_idx * (SEQ * HID) + h * (SEQ * HDIM)
                         + s_idx * HDIM + tx * 4) = out;
        }
    }
}

// ---------------------------------------------------------------------------
// Fused gaussian-score attention (no softmax):
//   ctx[i] = sum_{j > i} exp(-0.5 * dot(dif_i, dif_j)) * v_j
// One block per (bh, 64-row q-tile); iterate k-tiles kt >= qt.
// LDS: Qs [d][r], KsPs [d][c] (aliased with P [j][r]), Vs [j][e]; pitch 68.
// ---------------------------------------------------------------------------
__global__ __launch_bounds__(256) void attn_k(const float* __restrict__ dif,
                                              const float* __restrict__ vh,
                                              float* __restrict__ ctx) {
    const int qt = blockIdx.x;     // 0..31  q-tile
    const int bh = blockIdx.y;     // 0..31  batch*head
    const float* D = dif + bh * (SEQ * HDIM);
    const float* V = vh  + bh * (SEQ * HDIM);

    __shared__ float Qs[64][68];    // [d][r]   dif_q transposed
    __shared__ float KsPs[64][68];  // [d][c] during S;  [j][r] as P during PV
    __shared__ float Vs[64][68];    // [j][e]

    const int t  = threadIdx.x;
    const int tx = t & 15;          // col group
    const int ty = t >> 4;          // row group
    const int i0 = qt * 64;

    // stage Q tile (transposed: Qs[d][r])
#pragma unroll
    for (int p = 0; p < 4; p++) {
        const int q  = t + p * 256;
        const int jr = q >> 4;      // row 0..63
        const int dq = q & 15;      // d float4
        float4 v4 = *(const float4*)(D + (i0 + jr) * HDIM + dq * 4);
        Qs[dq * 4 + 0][jr] = v4.x;
        Qs[dq * 4 + 1][jr] = v4.y;
        Qs[dq * 4 + 2][jr] = v4.z;
        Qs[dq * 4 + 3][jr] = v4.w;
    }

    float acc[4][4] = {};

    for (int kt = qt; kt < SEQ / 64; kt++) {
        const int j0 = kt * 64;
        __syncthreads();   // prior iteration reads (and Qs staging) complete

        // stage K tile transposed + V tile natural
#pragma unroll
        for (int p = 0; p < 4; p++) {
            const int q  = t + p * 256;
            const int jr = q >> 4;
            const int dq = q & 15;
            float4 k4 = *(const float4*)(D + (j0 + jr) * HDIM + dq * 4);
            KsPs[dq * 4 + 0][jr] = k4.x;
            KsPs[dq * 4 + 1][jr] = k4.y;
            KsPs[dq * 4 + 2][jr] = k4.z;
            KsPs[dq * 4 + 3][jr] = k4.w;
            float4 v4 = *(const float4*)(V + (j0 + jr) * HDIM + dq * 4);
            *(float4*)(&Vs[jr][dq * 4]) = v4;
        }
        __syncthreads();

        // S-tile: sc[i][j] = dot(dif_{i0+r}, dif_{j0+c})
        float sc[4][4] = {};
#pragma unroll
        for (int d = 0; d < 64; d++) {
            float4 qv = *(const float4*)(&Qs[d][ty * 4]);
            float4 kv = *(const float4*)(&KsPs[d][tx * 4]);
            float qr[4] = {qv.x, qv.y, qv.z, qv.w};
            float kr[4] = {kv.x, kv.y, kv.z, kv.w};
#pragma unroll
            for (int i = 0; i < 4; i++)
#pragma unroll
                for (int j = 0; j < 4; j++)
                    sc[i][j] += qr[i] * kr[j];
        }

        // exp + strict-upper mask (only diagonal tile is partial)
        float pr[4][4];
        if (kt == qt) {
#pragma unroll
            for (int i = 0; i < 4; i++)
#pragma unroll
                for (int j = 0; j < 4; j++)
                    pr[i][j] = (tx * 4 + j > ty * 4 + i)
                                   ? __expf(-0.5f * sc[i][j]) : 0.0f;
        } else {
#pragma unroll
            for (int i = 0; i < 4; i++)
#pragma unroll
                for (int j = 0; j < 4; j++)
                    pr[i][j] = __expf(-0.5f * sc[i][j]);
        }

        __syncthreads();   // everyone done reading KsPs as K

        // write P into the K buffer, layout [j][r]
#pragma unroll
        for (int j = 0; j < 4; j++) {
            float4 pv = {pr[0][j], pr[1][j], pr[2][j], pr[3][j]};
            *(float4*)(&KsPs[tx * 4 + j][ty * 4]) = pv;
        }
        __syncthreads();

        // ctx[r][e] += sum_j P[r][j] * V[j][e]
#pragma unroll
        for (int j = 0; j < 64; j++) {
            float4 pv = *(const float4*)(&KsPs[j][ty * 4]);
            float4 vv = *(const float4*)(&Vs[j][tx * 4]);
            float p4[4] = {pv.x, pv.y, pv.z, pv.w};
            float v4[4] = {vv.x, vv.y, vv.z, vv.w};
#pragma unroll
            for (int i = 0; i < 4; i++)
#pragma unroll
                for (int jj = 0; jj < 4; jj++)
                    acc[i][jj] += p4[i] * v4[jj];
        }
    }

    // write ctx in [B,S,H] layout (n = h*64 + e)
    const int b_idx = bh >> 4;
    const int h     = bh & 15;
#pragma unroll
    for (int i = 0; i < 4; i++) {
        const int srow = i0 + ty * 4 + i;
        float4 out = {acc[i][0], acc[i][1], acc[i][2], acc[i][3]};
        *(float4*)(ctx + (b_idx * SEQ + srow) * HID + h * HDIM + tx * 4) = out;
    }
}

// ---------------------------------------------------------------------------
extern "C" void kernel_launch(void* const* d_in, const int* in_sizes, int n_in,
                              void* d_out, int out_size, void* d_ws, size_t ws_size,
                              hipStream_t stream) {
    const float* x  = (const float*)d_in[0];
    const float* Wq = (const float*)d_in[1];
    const float* bq = (const float*)d_in[2];
    const float* Wk = (const float*)d_in[3];
    const float* bk = (const float*)d_in[4];
    const float* Wv = (const float*)d_in[5];
    const float* bv = (const float*)d_in[6];
    const float* Wo = (const float*)d_in[7];
    const float* bo = (const float*)d_in[8];
    float* out = (float*)d_out;

    float* ws  = (float*)d_ws;
    float* dif = ws;                         // [B, nh, S, hd]  4 Mi floats
    float* vh  = ws + (size_t)MTOT * HID;    // [B, nh, S, hd]
    float* ctx = ws + (size_t)2 * MTOT * HID;// [B, S, H]

    dim3 gemm_grid(MTOT / 64, HID / 64);
    // dif = x @ (Wq - Wk) + (bq - bk), head-split
    gemm_k<2><<<gemm_grid, 256, 0, stream>>>(x, Wq, Wk, bq, bk, dif);
    // v = x @ Wv + bv, head-split
    gemm_k<1><<<gemm_grid, 256, 0, stream>>>(x, Wv, nullptr, bv, nullptr, vh);
    // fused attention
    attn_k<<<dim3(SEQ / 64, BH), 256, 0, stream>>>(dif, vh, ctx);
    // out = ctx @ Wo + bo  (6 args: A, W, W2, bias, bias2, C)
    gemm_k<0><<<gemm_grid, 256, 0, stream>>>(ctx, Wo, nullptr, bo, nullptr, out);
}

// Round 4
// 542.140 us; speedup vs baseline: 1.6905x; 1.6905x over previous
//
#include <hip/hip_runtime.h>
#include <math.h>

// Problem constants
constexpr int BATCH = 2;
constexpr int SEQ   = 2048;
constexpr int HID   = 1024;
constexpr int HDIM  = 64;
constexpr int MTOT  = BATCH * SEQ;        // 4096
constexpr int BH    = 32;                 // batch * heads

typedef short bf16x8 __attribute__((ext_vector_type(8)));
typedef float f32x4  __attribute__((ext_vector_type(4)));

__device__ __forceinline__ unsigned short bf_rne(float x) {
    unsigned u = __float_as_uint(x);
    return (unsigned short)((u + 0x7FFFu + ((u >> 16) & 1u)) >> 16);
}
__device__ __forceinline__ float bf2f(unsigned short h) {
    return __uint_as_float(((unsigned)h) << 16);
}

// ---------------------------------------------------------------------------
// fp32 GEMM: C = A[M,1024] @ W[1024,1024] + bias (unchanged from R3 baseline)
// MODE 0: row-major out; MODE 1: head-split; MODE 2: W-W2 / bias-bias2 fused
// ---------------------------------------------------------------------------
template<int MODE>
__global__ __launch_bounds__(256) void gemm_k(const float* __restrict__ A,
                                              const float* __restrict__ W,
                                              const float* __restrict__ W2,
                                              const float* __restrict__ bias,
                                              const float* __restrict__ bias2,
                                              float* __restrict__ C) {
    __shared__ float As[16][68];
    __shared__ float Bs[16][68];

    const int t  = threadIdx.x;
    const int m0 = blockIdx.x * 64;
    const int n0 = blockIdx.y * 64;
    const int tx = t & 15;
    const int ty = t >> 4;

    const int arow = t >> 2;
    const int akq  = t & 3;
    const int bkr  = t >> 4;
    const int bnq  = t & 15;

    float acc[4][4] = {};

    for (int k0 = 0; k0 < HID; k0 += 16) {
        float4 a4 = *(const float4*)(A + (m0 + arow) * HID + k0 + akq * 4);
        float4 b4 = *(const float4*)(W + (k0 + bkr) * HID + n0 + bnq * 4);
        if (MODE == 2) {
            float4 c4 = *(const float4*)(W2 + (k0 + bkr) * HID + n0 + bnq * 4);
            b4.x -= c4.x; b4.y -= c4.y; b4.z -= c4.z; b4.w -= c4.w;
        }
        __syncthreads();
        As[akq * 4 + 0][arow] = a4.x;
        As[akq * 4 + 1][arow] = a4.y;
        As[akq * 4 + 2][arow] = a4.z;
        As[akq * 4 + 3][arow] = a4.w;
        *(float4*)(&Bs[bkr][bnq * 4]) = b4;
        __syncthreads();

#pragma unroll
        for (int kk = 0; kk < 16; kk++) {
            float4 av = *(const float4*)(&As[kk][ty * 4]);
            float4 bv = *(const float4*)(&Bs[kk][tx * 4]);
            float ar[4] = {av.x, av.y, av.z, av.w};
            float br[4] = {bv.x, bv.y, bv.z, bv.w};
#pragma unroll
            for (int i = 0; i < 4; i++)
#pragma unroll
                for (int j = 0; j < 4; j++)
                    acc[i][j] += ar[i] * br[j];
        }
    }

    float4 bv = *(const float4*)(bias + n0 + tx * 4);
    if (MODE == 2) {
        float4 b2 = *(const float4*)(bias2 + n0 + tx * 4);
        bv.x -= b2.x; bv.y -= b2.y; bv.z -= b2.z; bv.w -= b2.w;
    }

#pragma unroll
    for (int i = 0; i < 4; i++) {
        const int m = m0 + ty * 4 + i;
        float4 out;
        out.x = acc[i][0] + bv.x;
        out.y = acc[i][1] + bv.y;
        out.z = acc[i][2] + bv.z;
        out.w = acc[i][3] + bv.w;
        if (MODE == 0) {
            *(float4*)(C + m * HID + n0 + tx * 4) = out;
        } else {
            const int b_idx = m >> 11;
            const int s_idx = m & 2047;
            const int h     = n0 >> 6;
            *(float4*)(C + b_idx * (SEQ * HID) + h * (SEQ * HDIM)
                         + s_idx * HDIM + tx * 4) = out;
        }
    }
}

// ---------------------------------------------------------------------------
// MFMA attention: ctx[i] = sum_{j>i} exp(-0.5*dot(dif_i,dif_j)) * v_j
// 16x16x32 bf16 MFMA; dif in hi/lo bf16 (QK^T: 3 terms), V hi/lo (PV: 2 terms),
// P single bf16 RNE. Block = (pair of q-tiles p, 31-p) x bh => 33 k-tiles each.
// LDS planes (pitch 72 shorts = 144B, 2-way bank aliasing = free):
//   Qhi,Qlo,Khi,Klo [row i/j][d],  Vhi,Vlo transposed [e][j],  P [i][j]
// ---------------------------------------------------------------------------
__global__ __launch_bounds__(256) void attn_mfma(const float* __restrict__ dif,
                                                 const float* __restrict__ vh,
                                                 float* __restrict__ ctx) {
    constexpr int LP = 72;          // row pitch in shorts
    constexpr int PS = 64 * LP;     // plane size
    __shared__ unsigned short lds[7 * PS];   // 63 KB
    unsigned short* Qhi = lds;
    unsigned short* Qlo = lds + PS;
    unsigned short* Khi = lds + 2 * PS;
    unsigned short* Klo = lds + 3 * PS;
    unsigned short* Vhi = lds + 4 * PS;      // [e][j]
    unsigned short* Vlo = lds + 5 * PS;      // [e][j]
    unsigned short* Pp  = lds + 6 * PS;      // [i][j], wave-private rows

    const int pq = blockIdx.x;      // 0..15 pair index
    const int bh = blockIdx.y;      // 0..31
    const float* D = dif + (size_t)bh * (SEQ * HDIM);
    const float* V = vh  + (size_t)bh * (SEQ * HDIM);
    const int b_idx = bh >> 4;
    const int h     = bh & 15;

    const int t    = threadIdx.x;
    const int l    = t & 63;
    const int w    = t >> 6;        // wave 0..3
    const int quad = l >> 4;
    const int ln   = l & 15;

    // V staging: thread owns 4x4 sub-block V[vj0..+3][ve0..+3]
    const int vj0 = 4 * (t & 15);
    const int ve0 = 4 * (t >> 4);

    for (int half = 0; half < 2; half++) {
        const int qt = half ? (31 - pq) : pq;
        const int i0 = qt * 64;
        __syncthreads();            // prior half's reads complete

        // ---- stage Q hi/lo ----
#pragma unroll
        for (int c = 0; c < 4; c++) {
            float4 q4 = *(const float4*)(D + i0 * 64 + c * 1024 + t * 4);
            const int row = (c * 1024 + t * 4) >> 6;
            const int col = (t * 4) & 63;
            unsigned short h0 = bf_rne(q4.x), h1 = bf_rne(q4.y),
                           h2 = bf_rne(q4.z), h3 = bf_rne(q4.w);
            unsigned short l0 = bf_rne(q4.x - bf2f(h0)), l1 = bf_rne(q4.y - bf2f(h1)),
                           l2 = bf_rne(q4.z - bf2f(h2)), l3 = bf_rne(q4.w - bf2f(h3));
            *(ushort4*)(Qhi + row * LP + col) = make_ushort4(h0, h1, h2, h3);
            *(ushort4*)(Qlo + row * LP + col) = make_ushort4(l0, l1, l2, l3);
        }

        f32x4 acc[4] = {};

        for (int kt = qt; kt < 32; kt++) {
            const int j0 = kt * 64;
            __syncthreads();        // prev iter frag reads done (also covers Q stage)

            // ---- load K tile + V tile ----
            float4 kv[4], vv[4];
#pragma unroll
            for (int c = 0; c < 4; c++)
                kv[c] = *(const float4*)(D + j0 * 64 + c * 1024 + t * 4);
#pragma unroll
            for (int i = 0; i < 4; i++)
                vv[i] = *(const float4*)(V + (j0 + vj0 + i) * 64 + ve0);

            // K hi/lo -> row-major
#pragma unroll
            for (int c = 0; c < 4; c++) {
                const int row = (c * 1024 + t * 4) >> 6;
                const int col = (t * 4) & 63;
                unsigned short h0 = bf_rne(kv[c].x), h1 = bf_rne(kv[c].y),
                               h2 = bf_rne(kv[c].z), h3 = bf_rne(kv[c].w);
                unsigned short l0 = bf_rne(kv[c].x - bf2f(h0)), l1 = bf_rne(kv[c].y - bf2f(h1)),
                               l2 = bf_rne(kv[c].z - bf2f(h2)), l3 = bf_rne(kv[c].w - bf2f(h3));
                *(ushort4*)(Khi + row * LP + col) = make_ushort4(h0, h1, h2, h3);
                *(ushort4*)(Klo + row * LP + col) = make_ushort4(l0, l1, l2, l3);
            }
            // V hi/lo -> transposed [e][j] via register 4x4 transpose
            {
                unsigned short th[4][4], tl[4][4];   // [j-sub][e-sub]
#pragma unroll
                for (int i = 0; i < 4; i++) {
                    float f[4] = {vv[i].x, vv[i].y, vv[i].z, vv[i].w};
#pragma unroll
                    for (int e = 0; e < 4; e++) {
                        unsigned short hh = bf_rne(f[e]);
                        th[i][e] = hh;
                        tl[i][e] = bf_rne(f[e] - bf2f(hh));
                    }
                }
#pragma unroll
                for (int e = 0; e < 4; e++) {
                    *(ushort4*)(Vhi + (ve0 + e) * LP + vj0) =
                        make_ushort4(th[0][e], th[1][e], th[2][e], th[3][e]);
                    *(ushort4*)(Vlo + (ve0 + e) * LP + vj0) =
                        make_ushort4(tl[0][e], tl[1][e], tl[2][e], tl[3][e]);
                }
            }
            __syncthreads();        // staging visible to all waves

            // ---- S = dif_q . dif_k^T  (hi*hi + lo*hi + hi*lo) ----
            f32x4 s[4] = {};
#pragma unroll
            for (int kh = 0; kh < 2; kh++) {
                bf16x8 aH = *(const bf16x8*)(Qhi + (w * 16 + ln) * LP + kh * 32 + quad * 8);
                bf16x8 aL = *(const bf16x8*)(Qlo + (w * 16 + ln) * LP + kh * 32 + quad * 8);
#pragma unroll
                for (int nt = 0; nt < 4; nt++) {
                    bf16x8 bH = *(const bf16x8*)(Khi + (nt * 16 + ln) * LP + kh * 32 + quad * 8);
                    bf16x8 bL = *(const bf16x8*)(Klo + (nt * 16 + ln) * LP + kh * 32 + quad * 8);
                    s[nt] = __builtin_amdgcn_mfma_f32_16x16x32_bf16(aH, bH, s[nt], 0, 0, 0);
                    s[nt] = __builtin_amdgcn_mfma_f32_16x16x32_bf16(aL, bH, s[nt], 0, 0, 0);
                    s[nt] = __builtin_amdgcn_mfma_f32_16x16x32_bf16(aH, bL, s[nt], 0, 0, 0);
                }
            }

            // ---- P = mask * exp(-0.5*s), store bf16 to wave-private LDS rows ----
            const bool full = (kt > qt);
#pragma unroll
            for (int nt = 0; nt < 4; nt++) {
#pragma unroll
                for (int r = 0; r < 4; r++) {
                    const int iloc = w * 16 + quad * 4 + r;
                    const int jloc = nt * 16 + ln;
                    float p = (full || (jloc > iloc)) ? __expf(-0.5f * s[nt][r]) : 0.0f;
                    Pp[iloc * LP + jloc] = bf_rne(p);
                }
            }
            // no barrier: Pp rows are wave-private; Vhi/Vlo covered by staging barrier

            // ---- ctx += P @ V  (P*(Vhi) + P*(Vlo)) ----
#pragma unroll
            for (int kh = 0; kh < 2; kh++) {
                bf16x8 aP = *(const bf16x8*)(Pp + (w * 16 + ln) * LP + kh * 32 + quad * 8);
#pragma unroll
                for (int nt = 0; nt < 4; nt++) {
                    bf16x8 bH = *(const bf16x8*)(Vhi + (nt * 16 + ln) * LP + kh * 32 + quad * 8);
                    bf16x8 bL = *(const bf16x8*)(Vlo + (nt * 16 + ln) * LP + kh * 32 + quad * 8);
                    acc[nt] = __builtin_amdgcn_mfma_f32_16x16x32_bf16(aP, bH, acc[nt], 0, 0, 0);
                    acc[nt] = __builtin_amdgcn_mfma_f32_16x16x32_bf16(aP, bL, acc[nt], 0, 0, 0);
                }
            }
        }

        // ---- write ctx [B,S,H] ----
#pragma unroll
        for (int nt = 0; nt < 4; nt++)
#pragma unroll
            for (int r = 0; r < 4; r++) {
                const int iloc = w * 16 + quad * 4 + r;
                ctx[(size_t)(b_idx * SEQ + i0 + iloc) * HID + h * 64 + nt * 16 + ln]
                    = acc[nt][r];
            }
    }
}

// ---------------------------------------------------------------------------
extern "C" void kernel_launch(void* const* d_in, const int* in_sizes, int n_in,
                              void* d_out, int out_size, void* d_ws, size_t ws_size,
                              hipStream_t stream) {
    const float* x  = (const float*)d_in[0];
    const float* Wq = (const float*)d_in[1];
    const float* bq = (const float*)d_in[2];
    const float* Wk = (const float*)d_in[3];
    const float* bk = (const float*)d_in[4];
    const float* Wv = (const float*)d_in[5];
    const float* bv = (const float*)d_in[6];
    const float* Wo = (const float*)d_in[7];
    const float* bo = (const float*)d_in[8];
    float* out = (float*)d_out;

    float* ws  = (float*)d_ws;
    float* dif = ws;                          // [B, nh, S, hd]
    float* vh  = ws + (size_t)MTOT * HID;     // [B, nh, S, hd]
    float* ctx = ws + (size_t)2 * MTOT * HID; // [B, S, H]

    dim3 gemm_grid(MTOT / 64, HID / 64);
    gemm_k<2><<<gemm_grid, 256, 0, stream>>>(x, Wq, Wk, bq, bk, dif);
    gemm_k<1><<<gemm_grid, 256, 0, stream>>>(x, Wv, nullptr, bv, nullptr, vh);
    attn_mfma<<<dim3(16, BH), 256, 0, stream>>>(dif, vh, ctx);
    gemm_k<0><<<gemm_grid, 256, 0, stream>>>(ctx, Wo, nullptr, bo, nullptr, out);
}

// Round 5
// 223.241 us; speedup vs baseline: 4.1054x; 2.4285x over previous
//
#include <hip/hip_runtime.h>
#include <math.h>

constexpr int SEQ  = 2048;
constexpr int HID  = 1024;
constexpr int MTOT = 4096;     // B*S
constexpr int BH   = 32;       // B*nh

typedef _Float16 f16;
typedef _Float16 f16x8 __attribute__((ext_vector_type(8)));
typedef float    f32x4 __attribute__((ext_vector_type(4)));

// ---------------------------------------------------------------------------
// convert x fp32 -> fp16, same layout [M][1024]
// ---------------------------------------------------------------------------
__global__ __launch_bounds__(256) void cvt_x(const float* __restrict__ in,
                                             f16* __restrict__ out) {
    const int i = (blockIdx.x * 256 + threadIdx.x) * 4;
    float4 v = *(const float4*)(in + i);
    f16 o[4] = {(f16)v.x, (f16)v.y, (f16)v.z, (f16)v.w};
    *(ushort4*)(out + i) = *(ushort4*)o;
}

// ---------------------------------------------------------------------------
// W [k][n] fp32 (optionally minus W2) -> WT [n][k] fp16   (64x64 LDS tiles)
// ---------------------------------------------------------------------------
template<int SUB>
__global__ __launch_bounds__(256) void cvt_wT(const float* __restrict__ W,
                                              const float* __restrict__ W2,
                                              f16* __restrict__ WT) {
    __shared__ f16 T[64][72];
    const int k0 = blockIdx.x * 64, n0 = blockIdx.y * 64;
    const int t = threadIdx.x;
    const int r  = t >> 4;          // k-row within 16-row slab
    const int c4 = (t & 15) * 4;    // n-col
#pragma unroll
    for (int rr = 0; rr < 64; rr += 16) {
        float4 w = *(const float4*)(W + (size_t)(k0 + rr + r) * HID + n0 + c4);
        if (SUB) {
            float4 w2 = *(const float4*)(W2 + (size_t)(k0 + rr + r) * HID + n0 + c4);
            w.x -= w2.x; w.y -= w2.y; w.z -= w2.z; w.w -= w2.w;
        }
        T[c4 + 0][rr + r] = (f16)w.x;
        T[c4 + 1][rr + r] = (f16)w.y;
        T[c4 + 2][rr + r] = (f16)w.z;
        T[c4 + 3][rr + r] = (f16)w.w;
    }
    __syncthreads();
#pragma unroll
    for (int pp = 0; pp < 2; pp++) {
        const int nr = pp * 32 + (t >> 3);
        const int kc = (t & 7) * 8;
        *(uint4*)(WT + (size_t)(n0 + nr) * HID + k0 + kc) = *(uint4*)(&T[nr][kc]);
    }
}

// ---------------------------------------------------------------------------
// MFMA fp16 GEMM: C = A[M][1024] @ BT[N][1024]^T + bias
// 128x128 tile, 4 waves (2x2 of 64x64), 16x16x32 f16 frags, BK=64.
// MODE 0: dif head-split f16 [bh][s][64], bias=b1-b2
// MODE 1: vT  f16 [bh][e][s] (transposed), bias=b1
// MODE 2: out fp32 [M][1024] = acc*65536 + b1   (ctx de-scaling)
// ---------------------------------------------------------------------------
template<int MODE>
__global__ __launch_bounds__(256) void mfma_gemm(const f16* __restrict__ A,
                                                 const f16* __restrict__ BT,
                                                 const float* __restrict__ b1,
                                                 const float* __restrict__ b2,
                                                 void* __restrict__ Cout) {
    __shared__ f16 As[128 * 72];
    __shared__ f16 Bs[128 * 72];
    const int t = threadIdx.x;
    const int m0 = blockIdx.x * 128, n0 = blockIdx.y * 128;
    const int w = t >> 6, l = t & 63, quad = l >> 4, ln = l & 15;
    const int wm = (w >> 1) * 64, wn = (w & 1) * 64;
    const int srow = t >> 1, shalf = (t & 1) * 32;

    f32x4 acc[4][4] = {};

    for (int k0 = 0; k0 < HID; k0 += 64) {
        __syncthreads();
        const f16* pa = A  + (size_t)(m0 + srow) * HID + k0 + shalf;
        const f16* pb = BT + (size_t)(n0 + srow) * HID + k0 + shalf;
        uint4 av0 = *(const uint4*)(pa),      av1 = *(const uint4*)(pa + 8);
        uint4 av2 = *(const uint4*)(pa + 16), av3 = *(const uint4*)(pa + 24);
        uint4 bv0 = *(const uint4*)(pb),      bv1 = *(const uint4*)(pb + 8);
        uint4 bv2 = *(const uint4*)(pb + 16), bv3 = *(const uint4*)(pb + 24);
        f16* da = As + srow * 72 + shalf;
        f16* db = Bs + srow * 72 + shalf;
        *(uint4*)(da)      = av0; *(uint4*)(da + 8)  = av1;
        *(uint4*)(da + 16) = av2; *(uint4*)(da + 24) = av3;
        *(uint4*)(db)      = bv0; *(uint4*)(db + 8)  = bv1;
        *(uint4*)(db + 16) = bv2; *(uint4*)(db + 24) = bv3;
        __syncthreads();

#pragma unroll
        for (int kh = 0; kh < 2; kh++) {
            f16x8 af[4], bf[4];
#pragma unroll
            for (int mt = 0; mt < 4; mt++)
                af[mt] = *(const f16x8*)(As + (wm + mt * 16 + ln) * 72 + kh * 32 + quad * 8);
#pragma unroll
            for (int nt = 0; nt < 4; nt++)
                bf[nt] = *(const f16x8*)(Bs + (wn + nt * 16 + ln) * 72 + kh * 32 + quad * 8);
#pragma unroll
            for (int mt = 0; mt < 4; mt++)
#pragma unroll
                for (int nt = 0; nt < 4; nt++)
                    acc[mt][nt] = __builtin_amdgcn_mfma_f32_16x16x32_f16(
                        af[mt], bf[nt], acc[mt][nt], 0, 0, 0);
        }
    }

#pragma unroll
    for (int mt = 0; mt < 4; mt++) {
#pragma unroll
        for (int nt = 0; nt < 4; nt++) {
            const int n = n0 + wn + nt * 16 + ln;
            const int m_base = m0 + wm + mt * 16 + quad * 4;
            if (MODE == 0) {
                const float bb = b1[n] - b2[n];
                const int h = n >> 6, e = n & 63;
#pragma unroll
                for (int r = 0; r < 4; r++) {
                    const int m = m_base + r;
                    const int b = m >> 11, s = m & 2047;
                    ((f16*)Cout)[((size_t)(b * 16 + h) * SEQ + s) * 64 + e] =
                        (f16)(acc[mt][nt][r] + bb);
                }
            } else if (MODE == 1) {
                const float bb = b1[n];
                const int h = n >> 6, e = n & 63;
                const int b = m_base >> 11, s0 = m_base & 2047;
                f16 o[4];
#pragma unroll
                for (int r = 0; r < 4; r++) o[r] = (f16)(acc[mt][nt][r] + bb);
                *(ushort4*)(&((f16*)Cout)[((size_t)(b * 16 + h) * 64 + e) * SEQ + s0]) =
                    *(ushort4*)o;
            } else {
                const float bb = b1[n];
#pragma unroll
                for (int r = 0; r < 4; r++) {
                    const int m = m_base + r;
                    ((float*)Cout)[(size_t)m * HID + n] = acc[mt][nt][r] * 65536.0f + bb;
                }
            }
        }
    }
}

// ---------------------------------------------------------------------------
// fp16 MFMA attention: ctx_scaled[i] = 2^-16 * sum_{j>i} exp(-0.5*dot) * v_j
// Inputs pre-converted: dif f16 [bh][s][64], vT f16 [bh][e][s].
// Block = q-tile pair (pq, 31-pq) x bh -> 33 k-tiles each (load-balanced).
// ---------------------------------------------------------------------------
__global__ __launch_bounds__(256) void attn_f16(const f16* __restrict__ dif,
                                                const f16* __restrict__ vT,
                                                f16* __restrict__ ctxs) {
    __shared__ f16 Qs[64 * 72];
    __shared__ f16 Ks[64 * 72];
    __shared__ f16 Vs[64 * 72];
    __shared__ f16 Ps[64 * 72];

    const int pq = blockIdx.x, bh = blockIdx.y;
    const f16* D  = dif + (size_t)bh * SEQ * 64;
    const f16* VT = vT  + (size_t)bh * 64 * SEQ;
    const int b = bh >> 4, h = bh & 15;
    const int t = threadIdx.x, w = t >> 6, l = t & 63, quad = l >> 4, ln = l & 15;

    for (int half = 0; half < 2; half++) {
        const int qt = half ? (31 - pq) : pq;
        const int i0 = qt * 64;
        __syncthreads();   // prior half's LDS reads complete

        // stage Q (pure copy, 8 KB)
#pragma unroll
        for (int rr = 0; rr < 2; rr++) {
            const int o = rr * 2048 + t * 8;
            uint4 v = *(const uint4*)(D + i0 * 64 + o);
            *(uint4*)(Qs + (o >> 6) * 72 + (o & 63)) = v;
        }

        f32x4 acc[4] = {};

        for (int kt = qt; kt < 32; kt++) {
            const int j0 = kt * 64;
            __syncthreads();   // prev iter frag reads done (covers Q stage too)

#pragma unroll
            for (int rr = 0; rr < 2; rr++) {
                const int o = rr * 2048 + t * 8;
                uint4 v = *(const uint4*)(D + j0 * 64 + o);
                *(uint4*)(Ks + (o >> 6) * 72 + (o & 63)) = v;
            }
            {
                const int e = t >> 2, c = (t & 3) * 16;
                uint4 v0 = *(const uint4*)(VT + (size_t)e * SEQ + j0 + c);
                uint4 v1 = *(const uint4*)(VT + (size_t)e * SEQ + j0 + c + 8);
                *(uint4*)(Vs + e * 72 + c)     = v0;
                *(uint4*)(Vs + e * 72 + c + 8) = v1;
            }
            __syncthreads();

            // S = Q . K^T
            f32x4 s[4] = {};
#pragma unroll
            for (int kh = 0; kh < 2; kh++) {
                f16x8 a = *(const f16x8*)(Qs + (w * 16 + ln) * 72 + kh * 32 + quad * 8);
#pragma unroll
                for (int nt = 0; nt < 4; nt++) {
                    f16x8 bfr = *(const f16x8*)(Ks + (nt * 16 + ln) * 72 + kh * 32 + quad * 8);
                    s[nt] = __builtin_amdgcn_mfma_f32_16x16x32_f16(a, bfr, s[nt], 0, 0, 0);
                }
            }

            // P = mask * exp(-0.5*s) * 2^-16  (fp16-safe), wave-private LDS rows
            const bool full = (kt > qt);
#pragma unroll
            for (int nt = 0; nt < 4; nt++)
#pragma unroll
                for (int r = 0; r < 4; r++) {
                    const int iloc = w * 16 + quad * 4 + r;
                    const int jloc = nt * 16 + ln;
                    float p = (full || (jloc > iloc))
                                  ? fminf(__expf(-0.5f * s[nt][r]) * 0x1p-16f, 60000.0f)
                                  : 0.0f;
                    Ps[iloc * 72 + jloc] = (f16)p;
                }

            // ctx += P @ V   (B-frag rows = vT rows e, k-contig in j)
#pragma unroll
            for (int kh = 0; kh < 2; kh++) {
                f16x8 a = *(const f16x8*)(Ps + (w * 16 + ln) * 72 + kh * 32 + quad * 8);
#pragma unroll
                for (int nt = 0; nt < 4; nt++) {
                    f16x8 bfr = *(const f16x8*)(Vs + (nt * 16 + ln) * 72 + kh * 32 + quad * 8);
                    acc[nt] = __builtin_amdgcn_mfma_f32_16x16x32_f16(a, bfr, acc[nt], 0, 0, 0);
                }
            }
        }

        // ctx_scaled fp16, row-major [M][1024] (k-contig for the out-GEMM)
#pragma unroll
        for (int nt = 0; nt < 4; nt++)
#pragma unroll
            for (int r = 0; r < 4; r++) {
                const int iloc = w * 16 + quad * 4 + r;
                ctxs[(size_t)(b * SEQ + i0 + iloc) * HID + h * 64 + nt * 16 + ln] =
                    (f16)acc[nt][r];
            }
    }
}

// ---------------------------------------------------------------------------
extern "C" void kernel_launch(void* const* d_in, const int* in_sizes, int n_in,
                              void* d_out, int out_size, void* d_ws, size_t ws_size,
                              hipStream_t stream) {
    const float* x  = (const float*)d_in[0];
    const float* Wq = (const float*)d_in[1];
    const float* bq = (const float*)d_in[2];
    const float* Wk = (const float*)d_in[3];
    const float* bk = (const float*)d_in[4];
    const float* Wv = (const float*)d_in[5];
    const float* bv = (const float*)d_in[6];
    const float* Wo = (const float*)d_in[7];
    const float* bo = (const float*)d_in[8];
    float* out = (float*)d_out;

    char* ws = (char*)d_ws;
    f16* xh    = (f16*)(ws);                     // 8 MB  [M][1024]
    f16* WqkT  = (f16*)(ws + (8 << 20));         // 2 MB  [n][k]
    f16* WvT   = (f16*)(ws + (10 << 20));        // 2 MB
    f16* WoT   = (f16*)(ws + (12 << 20));        // 2 MB
    f16* dif   = (f16*)(ws + (14 << 20));        // 8 MB  [bh][s][64]
    f16* vT    = (f16*)(ws + (22 << 20));        // 8 MB  [bh][e][s]
    f16* ctxs  = (f16*)(ws + (30 << 20));        // 8 MB  [M][1024] (x 2^-16)

    cvt_x<<<MTOT * HID / 1024, 256, 0, stream>>>(x, xh);
    dim3 wtg(16, 16);
    cvt_wT<1><<<wtg, 256, 0, stream>>>(Wq, Wk, WqkT);
    cvt_wT<0><<<wtg, 256, 0, stream>>>(Wv, nullptr, WvT);
    cvt_wT<0><<<wtg, 256, 0, stream>>>(Wo, nullptr, WoT);

    dim3 gg(MTOT / 128, HID / 128);
    mfma_gemm<0><<<gg, 256, 0, stream>>>(xh, WqkT, bq, bk, dif);
    mfma_gemm<1><<<gg, 256, 0, stream>>>(xh, WvT, bv, nullptr, vT);
    attn_f16<<<dim3(16, BH), 256, 0, stream>>>(dif, vT, ctxs);
    mfma_gemm<2><<<gg, 256, 0, stream>>>(ctxs, WoT, bo, nullptr, out);
}

// Round 6
// 191.414 us; speedup vs baseline: 4.7880x; 1.1663x over previous
//
#include <hip/hip_runtime.h>
#include <math.h>

constexpr int SEQ  = 2048;
constexpr int HID  = 1024;
constexpr int MTOT = 4096;     // B*S
constexpr int BH   = 32;       // B*nh

typedef _Float16 f16;
typedef _Float16 f16x8 __attribute__((ext_vector_type(8)));
typedef float    f32x4 __attribute__((ext_vector_type(4)));

// ---------------------------------------------------------------------------
// convert x fp32 -> fp16, same layout [M][1024]
// ---------------------------------------------------------------------------
__global__ __launch_bounds__(256) void cvt_x(const float* __restrict__ in,
                                             f16* __restrict__ out) {
    const int i = (blockIdx.x * 256 + threadIdx.x) * 4;
    float4 v = *(const float4*)(in + i);
    f16 o[4] = {(f16)v.x, (f16)v.y, (f16)v.z, (f16)v.w};
    *(ushort4*)(out + i) = *(ushort4*)o;
}

// ---------------------------------------------------------------------------
// W [k][n] fp32 (optionally minus W2) -> WT [n][k] fp16   (64x64 LDS tiles)
// ---------------------------------------------------------------------------
template<int SUB>
__global__ __launch_bounds__(256) void cvt_wT(const float* __restrict__ W,
                                              const float* __restrict__ W2,
                                              f16* __restrict__ WT) {
    __shared__ f16 T[64][72];
    const int k0 = blockIdx.x * 64, n0 = blockIdx.y * 64;
    const int t = threadIdx.x;
    const int r  = t >> 4;
    const int c4 = (t & 15) * 4;
#pragma unroll
    for (int rr = 0; rr < 64; rr += 16) {
        float4 w = *(const float4*)(W + (size_t)(k0 + rr + r) * HID + n0 + c4);
        if (SUB) {
            float4 w2 = *(const float4*)(W2 + (size_t)(k0 + rr + r) * HID + n0 + c4);
            w.x -= w2.x; w.y -= w2.y; w.z -= w2.z; w.w -= w2.w;
        }
        T[c4 + 0][rr + r] = (f16)w.x;
        T[c4 + 1][rr + r] = (f16)w.y;
        T[c4 + 2][rr + r] = (f16)w.z;
        T[c4 + 3][rr + r] = (f16)w.w;
    }
    __syncthreads();
#pragma unroll
    for (int pp = 0; pp < 2; pp++) {
        const int nr = pp * 32 + (t >> 3);
        const int kc = (t & 7) * 8;
        *(uint4*)(WT + (size_t)(n0 + nr) * HID + k0 + kc) = *(uint4*)(&T[nr][kc]);
    }
}

// ---------------------------------------------------------------------------
// Fused projection GEMM (dif + vT): N=2048 virtual (first 1024 -> dif, rest -> vT)
// 128x128 tile, 4 waves, 16x16x32 f16, BK=64, global->reg prefetch pipeline.
// ---------------------------------------------------------------------------
__global__ __launch_bounds__(256) void proj_gemm(const f16* __restrict__ A,
                                                 const f16* __restrict__ WqkT,
                                                 const f16* __restrict__ WvT,
                                                 const float* __restrict__ bq,
                                                 const float* __restrict__ bk,
                                                 const float* __restrict__ bv,
                                                 f16* __restrict__ dif,
                                                 f16* __restrict__ vT) {
    __shared__ f16 As[128 * 72];
    __shared__ f16 Bs[128 * 72];
    const int t = threadIdx.x;
    const int m0  = blockIdx.x * 128;
    const int n0g = blockIdx.y * 128;
    const bool isv = (n0g >= HID);
    const f16* BT = isv ? WvT : WqkT;
    const int n0 = n0g & (HID - 1);
    const int w = t >> 6, l = t & 63, quad = l >> 4, ln = l & 15;
    const int wm = (w >> 1) * 64, wn = (w & 1) * 64;
    const int srow = t >> 1, shalf = (t & 1) * 32;

    const f16* pa = A  + (size_t)(m0 + srow) * HID + shalf;
    const f16* pb = BT + (size_t)(n0 + srow) * HID + shalf;

    uint4 ar0 = *(const uint4*)(pa),      ar1 = *(const uint4*)(pa + 8);
    uint4 ar2 = *(const uint4*)(pa + 16), ar3 = *(const uint4*)(pa + 24);
    uint4 br0 = *(const uint4*)(pb),      br1 = *(const uint4*)(pb + 8);
    uint4 br2 = *(const uint4*)(pb + 16), br3 = *(const uint4*)(pb + 24);

    f32x4 acc[4][4] = {};

    for (int k0 = 0; k0 < HID; k0 += 64) {
        __syncthreads();
        f16* da = As + srow * 72 + shalf;
        f16* db = Bs + srow * 72 + shalf;
        *(uint4*)(da)      = ar0; *(uint4*)(da + 8)  = ar1;
        *(uint4*)(da + 16) = ar2; *(uint4*)(da + 24) = ar3;
        *(uint4*)(db)      = br0; *(uint4*)(db + 8)  = br1;
        *(uint4*)(db + 16) = br2; *(uint4*)(db + 24) = br3;
        __syncthreads();
        if (k0 + 64 < HID) {   // prefetch next slab while MFMAs run
            const f16* qa = pa + k0 + 64;
            const f16* qb = pb + k0 + 64;
            ar0 = *(const uint4*)(qa);      ar1 = *(const uint4*)(qa + 8);
            ar2 = *(const uint4*)(qa + 16); ar3 = *(const uint4*)(qa + 24);
            br0 = *(const uint4*)(qb);      br1 = *(const uint4*)(qb + 8);
            br2 = *(const uint4*)(qb + 16); br3 = *(const uint4*)(qb + 24);
        }
#pragma unroll
        for (int kh = 0; kh < 2; kh++) {
            f16x8 af[4], bf[4];
#pragma unroll
            for (int mt = 0; mt < 4; mt++)
                af[mt] = *(const f16x8*)(As + (wm + mt * 16 + ln) * 72 + kh * 32 + quad * 8);
#pragma unroll
            for (int nt = 0; nt < 4; nt++)
                bf[nt] = *(const f16x8*)(Bs + (wn + nt * 16 + ln) * 72 + kh * 32 + quad * 8);
#pragma unroll
            for (int mt = 0; mt < 4; mt++)
#pragma unroll
                for (int nt = 0; nt < 4; nt++)
                    acc[mt][nt] = __builtin_amdgcn_mfma_f32_16x16x32_f16(
                        af[mt], bf[nt], acc[mt][nt], 0, 0, 0);
        }
    }

#pragma unroll
    for (int mt = 0; mt < 4; mt++) {
#pragma unroll
        for (int nt = 0; nt < 4; nt++) {
            const int nl = n0 + wn + nt * 16 + ln;      // 0..1023 within matrix
            const int m_base = m0 + wm + mt * 16 + quad * 4;
            const int h = nl >> 6, e = nl & 63;
            if (!isv) {
                const float bb = bq[nl] - bk[nl];
#pragma unroll
                for (int r = 0; r < 4; r++) {
                    const int m = m_base + r;
                    const int b = m >> 11, s = m & 2047;
                    dif[((size_t)(b * 16 + h) * SEQ + s) * 64 + e] =
                        (f16)(acc[mt][nt][r] + bb);
                }
            } else {
                const float bb = bv[nl];
                const int b = m_base >> 11, s0 = m_base & 2047;
                f16 o[4];
#pragma unroll
                for (int r = 0; r < 4; r++) o[r] = (f16)(acc[mt][nt][r] + bb);
                *(ushort4*)(&vT[((size_t)(b * 16 + h) * 64 + e) * SEQ + s0]) =
                    *(ushort4*)o;
            }
        }
    }
}

// ---------------------------------------------------------------------------
// Output GEMM: out[M][1024] = (C0+C1)[M][1024] @ WoT^T * 65536 + bo
// 128x64 tile -> grid 32x16 = 512 blocks (2/CU). Pipelined staging.
// ---------------------------------------------------------------------------
__global__ __launch_bounds__(256) void out_gemm(const f16* __restrict__ C0,
                                                const f16* __restrict__ C1,
                                                const f16* __restrict__ WoT,
                                                const float* __restrict__ bo,
                                                float* __restrict__ out) {
    __shared__ f16 As[128 * 72];
    __shared__ f16 Bs[64 * 72];
    const int t = threadIdx.x;
    const int m0 = blockIdx.x * 128, n0 = blockIdx.y * 64;
    const int w = t >> 6, l = t & 63, quad = l >> 4, ln = l & 15;
    const int wm = (w >> 1) * 64, wn = (w & 1) * 32;
    const int arow = t >> 1, ahalf = (t & 1) * 32;
    const int brow = t >> 2, boff = (t & 3) * 16;

    const f16* pa0 = C0  + (size_t)(m0 + arow) * HID + ahalf;
    const f16* pa1 = C1  + (size_t)(m0 + arow) * HID + ahalf;
    const f16* pb  = WoT + (size_t)(n0 + brow) * HID + boff;

    f16x8 a0 = *(const f16x8*)(pa0)      + *(const f16x8*)(pa1);
    f16x8 a1 = *(const f16x8*)(pa0 + 8)  + *(const f16x8*)(pa1 + 8);
    f16x8 a2 = *(const f16x8*)(pa0 + 16) + *(const f16x8*)(pa1 + 16);
    f16x8 a3 = *(const f16x8*)(pa0 + 24) + *(const f16x8*)(pa1 + 24);
    uint4 b0 = *(const uint4*)(pb), b1 = *(const uint4*)(pb + 8);

    f32x4 acc[4][2] = {};

    for (int k0 = 0; k0 < HID; k0 += 64) {
        __syncthreads();
        f16* da = As + arow * 72 + ahalf;
        *(f16x8*)(da)      = a0; *(f16x8*)(da + 8)  = a1;
        *(f16x8*)(da + 16) = a2; *(f16x8*)(da + 24) = a3;
        f16* db = Bs + brow * 72 + boff;
        *(uint4*)(db) = b0; *(uint4*)(db + 8) = b1;
        __syncthreads();
        if (k0 + 64 < HID) {
            const int kn = k0 + 64;
            a0 = *(const f16x8*)(pa0 + kn)      + *(const f16x8*)(pa1 + kn);
            a1 = *(const f16x8*)(pa0 + kn + 8)  + *(const f16x8*)(pa1 + kn + 8);
            a2 = *(const f16x8*)(pa0 + kn + 16) + *(const f16x8*)(pa1 + kn + 16);
            a3 = *(const f16x8*)(pa0 + kn + 24) + *(const f16x8*)(pa1 + kn + 24);
            b0 = *(const uint4*)(pb + kn); b1 = *(const uint4*)(pb + kn + 8);
        }
#pragma unroll
        for (int kh = 0; kh < 2; kh++) {
            f16x8 af[4], bf[2];
#pragma unroll
            for (int mt = 0; mt < 4; mt++)
                af[mt] = *(const f16x8*)(As + (wm + mt * 16 + ln) * 72 + kh * 32 + quad * 8);
#pragma unroll
            for (int nt = 0; nt < 2; nt++)
                bf[nt] = *(const f16x8*)(Bs + (wn + nt * 16 + ln) * 72 + kh * 32 + quad * 8);
#pragma unroll
            for (int mt = 0; mt < 4; mt++)
#pragma unroll
                for (int nt = 0; nt < 2; nt++)
                    acc[mt][nt] = __builtin_amdgcn_mfma_f32_16x16x32_f16(
                        af[mt], bf[nt], acc[mt][nt], 0, 0, 0);
        }
    }

#pragma unroll
    for (int mt = 0; mt < 4; mt++)
#pragma unroll
        for (int nt = 0; nt < 2; nt++) {
            const int n = n0 + wn + nt * 16 + ln;
            const float bb = bo[n];
            const int m_base = m0 + wm + mt * 16 + quad * 4;
#pragma unroll
            for (int r = 0; r < 4; r++)
                out[(size_t)(m_base + r) * HID + n] =
                    acc[mt][nt][r] * 65536.0f + bb;
        }
}

// ---------------------------------------------------------------------------
// fp16 MFMA attention, k-split x2: block (pq, bh, ks) handles q-tiles
// (pq, 31-pq), k-tiles kt = qt+ks, qt+ks+2, ... Partial ctx -> buffer ks.
// Grid 16x32x2 = 1024 blocks = 4/CU.
// ---------------------------------------------------------------------------
__global__ __launch_bounds__(256) void attn_f16(const f16* __restrict__ dif,
                                                const f16* __restrict__ vT,
                                                f16* __restrict__ ctx0,
                                                f16* __restrict__ ctx1) {
    __shared__ f16 Qs[64 * 72];
    __shared__ f16 Ks[64 * 72];
    __shared__ f16 Vs[64 * 72];
    __shared__ f16 Ps[64 * 72];

    const int pq = blockIdx.x, bh = blockIdx.y, ks = blockIdx.z;
    f16* Cout = ks ? ctx1 : ctx0;
    const f16* D  = dif + (size_t)bh * SEQ * 64;
    const f16* VT = vT  + (size_t)bh * 64 * SEQ;
    const int b = bh >> 4, h = bh & 15;
    const int t = threadIdx.x, w = t >> 6, l = t & 63, quad = l >> 4, ln = l & 15;
    const int ve = t >> 2, vc = (t & 3) * 16;

    for (int half = 0; half < 2; half++) {
        const int qt = half ? (31 - pq) : pq;
        const int i0 = qt * 64;
        __syncthreads();   // prior half's LDS reads complete

        // stage Q (pure copy, 8 KB)
#pragma unroll
        for (int rr = 0; rr < 2; rr++) {
            const int o = rr * 2048 + t * 8;
            uint4 v = *(const uint4*)(D + i0 * 64 + o);
            *(uint4*)(Qs + (o >> 6) * 72 + (o & 63)) = v;
        }

        f32x4 acc[4] = {};
        const int kt0 = qt + ks;

        // prefetch first K/V slab into regs
        uint4 kr0, kr1, vr0, vr1;
        if (kt0 < 32) {
            const int j0 = kt0 * 64;
            kr0 = *(const uint4*)(D + j0 * 64 + t * 8);
            kr1 = *(const uint4*)(D + j0 * 64 + 2048 + t * 8);
            vr0 = *(const uint4*)(VT + (size_t)ve * SEQ + j0 + vc);
            vr1 = *(const uint4*)(VT + (size_t)ve * SEQ + j0 + vc + 8);
        }

        for (int kt = kt0; kt < 32; kt += 2) {
            __syncthreads();   // prev iter frag reads done (covers Q stage too)

            {   // write staged regs -> LDS
                const int o0 = t * 8, o1 = 2048 + t * 8;
                *(uint4*)(Ks + (o0 >> 6) * 72 + (o0 & 63)) = kr0;
                *(uint4*)(Ks + (o1 >> 6) * 72 + (o1 & 63)) = kr1;
                *(uint4*)(Vs + ve * 72 + vc)     = vr0;
                *(uint4*)(Vs + ve * 72 + vc + 8) = vr1;
            }
            __syncthreads();

            if (kt + 2 < 32) {   // prefetch next slab
                const int j2 = (kt + 2) * 64;
                kr0 = *(const uint4*)(D + j2 * 64 + t * 8);
                kr1 = *(const uint4*)(D + j2 * 64 + 2048 + t * 8);
                vr0 = *(const uint4*)(VT + (size_t)ve * SEQ + j2 + vc);
                vr1 = *(const uint4*)(VT + (size_t)ve * SEQ + j2 + vc + 8);
            }

            // S = Q . K^T
            f32x4 s[4] = {};
#pragma unroll
            for (int kh = 0; kh < 2; kh++) {
                f16x8 a = *(const f16x8*)(Qs + (w * 16 + ln) * 72 + kh * 32 + quad * 8);
#pragma unroll
                for (int nt = 0; nt < 4; nt++) {
                    f16x8 bfr = *(const f16x8*)(Ks + (nt * 16 + ln) * 72 + kh * 32 + quad * 8);
                    s[nt] = __builtin_amdgcn_mfma_f32_16x16x32_f16(a, bfr, s[nt], 0, 0, 0);
                }
            }

            // P = mask * exp(-0.5*s) * 2^-16, wave-private LDS rows
            const bool full = (kt > qt);
#pragma unroll
            for (int nt = 0; nt < 4; nt++)
#pragma unroll
                for (int r = 0; r < 4; r++) {
                    const int iloc = w * 16 + quad * 4 + r;
                    const int jloc = nt * 16 + ln;
                    float p = (full || (jloc > iloc))
                                  ? fminf(__expf(-0.5f * s[nt][r]) * 0x1p-16f, 60000.0f)
                                  : 0.0f;
                    Ps[iloc * 72 + jloc] = (f16)p;
                }

            // ctx += P @ V
#pragma unroll
            for (int kh = 0; kh < 2; kh++) {
                f16x8 a = *(const f16x8*)(Ps + (w * 16 + ln) * 72 + kh * 32 + quad * 8);
#pragma unroll
                for (int nt = 0; nt < 4; nt++) {
                    f16x8 bfr = *(const f16x8*)(Vs + (nt * 16 + ln) * 72 + kh * 32 + quad * 8);
                    acc[nt] = __builtin_amdgcn_mfma_f32_16x16x32_f16(a, bfr, acc[nt], 0, 0, 0);
                }
            }
        }

        // partial ctx (scaled 2^-16) fp16, row-major [M][1024]
#pragma unroll
        for (int nt = 0; nt < 4; nt++)
#pragma unroll
            for (int r = 0; r < 4; r++) {
                const int iloc = w * 16 + quad * 4 + r;
                Cout[(size_t)(b * SEQ + i0 + iloc) * HID + h * 64 + nt * 16 + ln] =
                    (f16)acc[nt][r];
            }
    }
}

// ---------------------------------------------------------------------------
extern "C" void kernel_launch(void* const* d_in, const int* in_sizes, int n_in,
                              void* d_out, int out_size, void* d_ws, size_t ws_size,
                              hipStream_t stream) {
    const float* x  = (const float*)d_in[0];
    const float* Wq = (const float*)d_in[1];
    const float* bq = (const float*)d_in[2];
    const float* Wk = (const float*)d_in[3];
    const float* bk = (const float*)d_in[4];
    const float* Wv = (const float*)d_in[5];
    const float* bv = (const float*)d_in[6];
    const float* Wo = (const float*)d_in[7];
    const float* bo = (const float*)d_in[8];
    float* out = (float*)d_out;

    char* ws = (char*)d_ws;
    f16* xh   = (f16*)(ws);               // 8 MB  [M][1024]
    f16* WqkT = (f16*)(ws + (8 << 20));   // 2 MB  [n][k]
    f16* WvT  = (f16*)(ws + (10 << 20));  // 2 MB
    f16* WoT  = (f16*)(ws + (12 << 20));  // 2 MB
    f16* dif  = (f16*)(ws + (14 << 20));  // 8 MB  [bh][s][64]
    f16* vT   = (f16*)(ws + (22 << 20));  // 8 MB  [bh][e][s]
    f16* ctx0 = (f16*)(ws + (30 << 20));  // 8 MB  partial (x 2^-16)
    f16* ctx1 = (f16*)(ws + (38 << 20));  // 8 MB  partial

    cvt_x<<<MTOT * HID / 1024, 256, 0, stream>>>(x, xh);
    dim3 wtg(16, 16);
    cvt_wT<1><<<wtg, 256, 0, stream>>>(Wq, Wk, WqkT);
    cvt_wT<0><<<wtg, 256, 0, stream>>>(Wv, nullptr, WvT);
    cvt_wT<0><<<wtg, 256, 0, stream>>>(Wo, nullptr, WoT);

    proj_gemm<<<dim3(MTOT / 128, 16), 256, 0, stream>>>(xh, WqkT, WvT,
                                                        bq, bk, bv, dif, vT);
    attn_f16<<<dim3(16, BH, 2), 256, 0, stream>>>(dif, vT, ctx0, ctx1);
    out_gemm<<<dim3(MTOT / 128, 16), 256, 0, stream>>>(ctx0, ctx1, WoT, bo, out);
}